// Round 5
// baseline (471.112 us; speedup 1.0000x reference)
//
#include <hip/hip_runtime.h>

// L=2048, S=2048, N=4, E=1024, H=16, HD=64
using f32x4  = __attribute__((ext_vector_type(4))) float;
using short8 = __attribute__((ext_vector_type(8))) short;
using short4v = __attribute__((ext_vector_type(4))) short;

__device__ __forceinline__ short f2bf(float f) {
  unsigned u = __float_as_uint(f);
  u += 0x7fffu + ((u >> 16) & 1u);   // RNE
  return (short)(u >> 16);
}

__device__ __forceinline__ void async16(const void* g, void* l) {
  __builtin_amdgcn_global_load_lds(
      (const __attribute__((address_space(1))) unsigned int*)g,
      (__attribute__((address_space(3))) unsigned int*)l, 16, 0, 0);
}

// ---------------- convert fp32 -> bf16 (optionally permute (L,N,E)->[n][l][e]) ----------------
__global__ void __launch_bounds__(256) cvt_kernel(const float* __restrict__ src,
                                                  short* __restrict__ dst,
                                                  int permute) {
  const int r = blockIdx.x;
  const int t = threadIdx.x;
  int srcRow = r;
  if (permute) { int n = r >> 11; int l = r & 2047; srcRow = l * 4 + n; }
  float4 v = *(const float4*)(src + (size_t)srcRow * 1024 + t * 4);
  short4v o;
  o.x = f2bf(v.x); o.y = f2bf(v.y); o.z = f2bf(v.z); o.w = f2bf(v.w);
  *(short4v*)(dst + (size_t)r * 1024 + t * 4) = o;
}

// ---------------- TN GEMM: C[M,1024] = A[M,1024] @ B[1024,1024]^T (+bias)(*scale) ----------------
template <bool F32OUT>
__global__ void __launch_bounds__(256) gemm_bt(const short* __restrict__ A0,
                                               const short* __restrict__ B0,
                                               const float* __restrict__ bias0,
                                               void* __restrict__ out0,
                                               long zA, long zB, long zBias, long zOut,
                                               float scale0) {
  __shared__ short As[128 * 32];
  __shared__ short Bs[128 * 32];
  const int bz = blockIdx.z;
  const short* A = A0 + (size_t)bz * zA;
  const short* B = B0 + (size_t)bz * zB;
  const float* bias = bias0 + (size_t)bz * zBias;
  const float scale = (bz == 0) ? scale0 : 1.0f;

  const int t = threadIdx.x;
  const int wave = t >> 6, lane = t & 63;
  const int quad = lane >> 4, li = lane & 15;
  const int wm = wave >> 1, wn = wave & 1;
  const int bm = blockIdx.y, bn = blockIdx.x;
  const short* Ablk = A + (size_t)bm * 128 * 1024;
  const short* Bblk = B + (size_t)bn * 128 * 1024;

  float bv[4];
#pragma unroll
  for (int nt = 0; nt < 4; nt++) bv[nt] = bias[bn * 128 + wn * 64 + nt * 16 + li];

  f32x4 acc[4][4];
#pragma unroll
  for (int mt = 0; mt < 4; mt++)
#pragma unroll
    for (int nt = 0; nt < 4; nt++) acc[mt][nt] = (f32x4){0.f, 0.f, 0.f, 0.f};

  for (int kk = 0; kk < 32; kk++) {
    const int k0 = kk * 32;
    __syncthreads();
#pragma unroll
    for (int r = 0; r < 2; r++) {
      int idx = r * 256 + t;
      int row = idx >> 2, pos = idx & 3;
      int c = pos ^ ((row >> 1) & 3);
      async16(Ablk + (size_t)row * 1024 + k0 + c * 8, &As[idx * 8]);
    }
#pragma unroll
    for (int r = 0; r < 2; r++) {
      int idx = r * 256 + t;
      int row = idx >> 2, pos = idx & 3;
      int c = pos ^ ((row >> 1) & 3);
      async16(Bblk + (size_t)row * 1024 + k0 + c * 8, &Bs[idx * 8]);
    }
    __syncthreads();

    short8 af[4], bf[4];
#pragma unroll
    for (int mt = 0; mt < 4; mt++) {
      int m = wm * 64 + mt * 16 + li;
      int pos = quad ^ ((m >> 1) & 3);
      af[mt] = *(const short8*)&As[m * 32 + pos * 8];
    }
#pragma unroll
    for (int nt = 0; nt < 4; nt++) {
      int nn = wn * 64 + nt * 16 + li;
      int pos = quad ^ ((nn >> 1) & 3);
      bf[nt] = *(const short8*)&Bs[nn * 32 + pos * 8];
    }
#pragma unroll
    for (int mt = 0; mt < 4; mt++)
#pragma unroll
      for (int nt = 0; nt < 4; nt++)
        acc[mt][nt] = __builtin_amdgcn_mfma_f32_16x16x32_bf16(af[mt], bf[nt], acc[mt][nt], 0, 0, 0);
  }

#pragma unroll
  for (int mt = 0; mt < 4; mt++)
#pragma unroll
    for (int nt = 0; nt < 4; nt++) {
      int cg = bn * 128 + wn * 64 + nt * 16 + li;
#pragma unroll
      for (int rr = 0; rr < 4; rr++) {
        int rg = bm * 128 + wm * 64 + mt * 16 + quad * 4 + rr;
        float v = (acc[mt][nt][rr] + bv[nt]) * scale;
        if (F32OUT)
          ((float*)out0)[(size_t)bz * zOut + (size_t)rg * 1024 + cg] = v;
        else
          ((short*)out0)[(size_t)bz * zOut + (size_t)rg * 1024 + cg] = f2bf(v);
      }
    }
}

// ---------------- V transpose: [n][s][e] -> [n][e][s] (bf16) ----------------
__global__ void __launch_bounds__(256) vtrans(const short* __restrict__ V,
                                              short* __restrict__ Vt) {
  __shared__ short tile[64][72];
  const int e0 = blockIdx.x * 64;
  const int s0 = blockIdx.y * 64;
  const int n = blockIdx.z;
  const int t = threadIdx.x;
#pragma unroll
  for (int r = 0; r < 2; r++) {
    int idx = r * 256 + t;
    int srow = idx >> 3, c = idx & 7;
    short8 v = *(const short8*)(V + (size_t)(n * 2048 + s0 + srow) * 1024 + e0 + c * 8);
    *(short8*)&tile[srow][c * 8] = v;
  }
  __syncthreads();
#pragma unroll
  for (int r = 0; r < 2; r++) {
    int idx = r * 256 + t;
    int erow = idx >> 3, c = idx & 7;
    short8 o;
#pragma unroll
    for (int j = 0; j < 8; j++) o[j] = tile[c * 8 + j][erow];
    *(short8*)(Vt + (size_t)(n * 1024 + e0 + erow) * 2048 + s0 + c * 8) = o;
  }
}

// ---------------- attn_ctx: head-parallel flash kernel (double-buffered staging) ----------------
// grid 1024: bid -> h=bid&15, n=(bid>>4)&3, lc=bid>>6 (16 chunks of 128 rows).
// 8 waves x 16 q-rows. K/V 64x64 tiles ping-pong staged in LDS (global_load_lds,
// XOR swizzle); prefetch of tile t+1 issued before computing tile t, so staging
// latency hides under QK/softmax/PV. One barrier per tile (its vmcnt(0) drain is
// the ready-signal for the prefetched buffer).
__global__ void __launch_bounds__(512, 4) attn_ctx(const short* __restrict__ Qws,
                                                   const short* __restrict__ Kws,
                                                   const short* __restrict__ Vtws,
                                                   short* __restrict__ Ctx,
                                                   float* __restrict__ Rden) {
  __shared__ short Ks0[64 * 64];
  __shared__ short Ks1[64 * 64];
  __shared__ short Vs0[64 * 64];
  __shared__ short Vs1[64 * 64];
  __shared__ short et[8][16][68];   // pad 68: quads land on distinct bank octets

  const int bid = blockIdx.x;
  const int h = bid & 15;
  const int n = (bid >> 4) & 3;
  const int lc = bid >> 6;
  const int t = threadIdx.x;
  const int wave = t >> 6, lane = t & 63;
  const int quad = lane >> 4, li = lane & 15;
  const int sw = li & 7;            // row&7 for fragment reads (row = x*16+li)
  const int l0 = lc * 128 + wave * 16;

  const size_t Kn = (size_t)n * 2048 * 1024;
  const size_t Vnb = ((size_t)n * 1024 + h * 64) * 2048;

  // persistent Q fragments (A-layout): rows l0+li, k = ks*32+quad*8
  short8 qf0 = *(const short8*)(Qws + Kn + (size_t)(l0 + li) * 1024 + h * 64 + quad * 8);
  short8 qf1 = *(const short8*)(Qws + Kn + (size_t)(l0 + li) * 1024 + h * 64 + 32 + quad * 8);

  // staging addresses: each wave stages 8 rows (1 KB) of K and of V per tile
  const int srow = lane >> 3;
  const int c = lane & 7;
  const int row8 = wave * 8 + srow;            // 0..63 tile row
  const int gch = c ^ (row8 & 7);              // XOR chunk swizzle
  const short* gK = Kws + Kn + (size_t)row8 * 1024 + h * 64 + gch * 8;
  const short* gV = Vtws + Vnb + (size_t)row8 * 2048 + gch * 8;
  short* lK0 = &Ks0[0] + wave * 512 + lane * 8;
  short* lK1 = &Ks1[0] + wave * 512 + lane * 8;
  short* lV0 = &Vs0[0] + wave * 512 + lane * 8;
  short* lV1 = &Vs1[0] + wave * 512 + lane * 8;

  f32x4 ctx[4];
  f32x4 den = (f32x4){0.f, 0.f, 0.f, 0.f};
#pragma unroll
  for (int nt = 0; nt < 4; nt++) ctx[nt] = (f32x4){0.f, 0.f, 0.f, 0.f};

#define CTX_COMPUTE(KS, VS) do {                                               \
    f32x4 sc[4];                                                               \
    _Pragma("unroll") for (int nts = 0; nts < 4; nts++)                        \
        sc[nts] = (f32x4){0.f, 0.f, 0.f, 0.f};                                 \
    _Pragma("unroll") for (int nts = 0; nts < 4; nts++) {                      \
      const int row = nts * 16 + li;                                           \
      short8 k0 = *(const short8*)&KS[row * 64 + ((quad ^ sw) << 3)];          \
      short8 k1 = *(const short8*)&KS[row * 64 + (((4 + quad) ^ sw) << 3)];    \
      sc[nts] = __builtin_amdgcn_mfma_f32_16x16x32_bf16(qf0, k0, sc[nts], 0, 0, 0); \
      sc[nts] = __builtin_amdgcn_mfma_f32_16x16x32_bf16(qf1, k1, sc[nts], 0, 0, 0); \
    }                                                                          \
    _Pragma("unroll") for (int nts = 0; nts < 4; nts++)                        \
      _Pragma("unroll") for (int rr = 0; rr < 4; rr++) {                       \
        float e = __expf(sc[nts][rr]);                                         \
        den[rr] += e;                                                          \
        et[wave][quad * 4 + rr][nts * 16 + li] = f2bf(e);                      \
      }                                                                        \
    asm volatile("s_waitcnt lgkmcnt(0)" ::: "memory");                         \
    short8 e0 = *(const short8*)&et[wave][li][quad * 8];                       \
    short8 e1 = *(const short8*)&et[wave][li][32 + quad * 8];                  \
    _Pragma("unroll") for (int nt = 0; nt < 4; nt++) {                         \
      const int row = nt * 16 + li;                                            \
      short8 v0 = *(const short8*)&VS[row * 64 + ((quad ^ sw) << 3)];          \
      short8 v1 = *(const short8*)&VS[row * 64 + (((4 + quad) ^ sw) << 3)];    \
      ctx[nt] = __builtin_amdgcn_mfma_f32_16x16x32_bf16(e0, v0, ctx[nt], 0, 0, 0); \
      ctx[nt] = __builtin_amdgcn_mfma_f32_16x16x32_bf16(e1, v1, ctx[nt], 0, 0, 0); \
    }                                                                          \
  } while (0)

  // prologue: stage tile 0 into buffer 0
  async16(gK, lK0); async16(gV, lV0);
  gK += 64 * 1024; gV += 64;

  for (int it = 0; it < 32; it += 2) {
    __syncthreads();                  // buf0 staged (vmcnt drained); buf1 reads done
    if (it + 1 < 32) { async16(gK, lK1); async16(gV, lV1); gK += 64 * 1024; gV += 64; }
    CTX_COMPUTE(Ks0, Vs0);
    __syncthreads();                  // buf1 staged; buf0 reads done
    if (it + 2 < 32) { async16(gK, lK0); async16(gV, lV0); gK += 64 * 1024; gV += 64; }
    CTX_COMPUTE(Ks1, Vs1);
  }
#undef CTX_COMPUTE

  // reduce denom over the 16 li lanes
#pragma unroll
  for (int off = 1; off < 16; off <<= 1)
#pragma unroll
    for (int rr = 0; rr < 4; rr++) den[rr] += __shfl_xor(den[rr], off);
  f32x4 rden;
#pragma unroll
  for (int rr = 0; rr < 4; rr++) rden[rr] = 1.0f / den[rr];

  if (li == 0) {
#pragma unroll
    for (int rr = 0; rr < 4; rr++)
      Rden[((size_t)n * 16 + h) * 2048 + l0 + quad * 4 + rr] = rden[rr];
  }

#pragma unroll
  for (int nt = 0; nt < 4; nt++)
#pragma unroll
    for (int rr = 0; rr < 4; rr++) {
      int l = l0 + quad * 4 + rr;
      float v = ctx[nt][rr] * rden[rr];
      Ctx[((size_t)l * 4 + n) * 1024 + h * 64 + nt * 16 + li] = f2bf(v);
    }
}

// ---------------- attn_w: weights output (LDS-tiled GEMM over heads, double-buffered) ---------
// grid 1024: xcd = bid&7 -> n = xcd>>1; u = ((bid>>3)<<1)|(xcd&1) in [0,256):
// lt = u>>4, st = u&15 -> 128l x 128s output tile. 8 waves: wm = wave>>2,
// wn = wave&3; wave tile 64l x 32s. Per head: Q-slice + K-slice (16 KB each)
// ping-pong staged via global_load_lds + XOR chunk swizzle; head h+1's stage is
// issued before computing head h (latency hidden under 16 MFMA + exp). One
// barrier per head.
__global__ void __launch_bounds__(512, 2) attn_w(const short* __restrict__ Qws,
                                                 const short* __restrict__ Kws,
                                                 const float* __restrict__ Rden,
                                                 float* __restrict__ Wout) {
  __shared__ short Qs0[128 * 64];
  __shared__ short Qs1[128 * 64];
  __shared__ short Ks20[128 * 64];
  __shared__ short Ks21[128 * 64];
  __shared__ __align__(16) float rl[16][128];   // [h][l-idx] 1/denominator

  const int bid = blockIdx.x;
  const int xcd = bid & 7;
  const int n = xcd >> 1;
  const int u = ((bid >> 3) << 1) | (xcd & 1);   // 0..255
  const int lt = u >> 4;                          // 0..15
  const int st = u & 15;                          // 0..15
  const int l0 = lt * 128;
  const int s0 = st * 128;
  const int t = threadIdx.x;
  const int wave = t >> 6, lane = t & 63;
  const int quad = lane >> 4, li = lane & 15;
  const int wm = wave >> 2, wn = wave & 3;

  const size_t Kn = (size_t)n * 2048 * 1024;
  const short* Qg = Qws + Kn + (size_t)l0 * 1024;
  const short* Kg = Kws + Kn + (size_t)s0 * 1024;

  // stage rden: 16 heads x 128 l-rows (8 KB), 4 floats/thread
  {
    int idx = t * 4;
    int hh = idx >> 7, ll = idx & 127;
    *(float4*)&rl[hh][ll] =
        *(const float4*)(Rden + ((size_t)n * 16 + hh) * 2048 + l0 + ll);
  }

  f32x4 ws[4][2];
#pragma unroll
  for (int mt = 0; mt < 4; mt++)
#pragma unroll
    for (int st2 = 0; st2 < 2; st2++) ws[mt][st2] = (f32x4){0.f, 0.f, 0.f, 0.f};

#define AW_STAGE(QS, KS, H) do {                                               \
    _Pragma("unroll") for (int r = 0; r < 2; r++) {                            \
      int idx = r * 512 + t;                                                   \
      int row = idx >> 3, pos = idx & 7;                                       \
      int cc = pos ^ (row & 7);                                                \
      async16(Qg + (size_t)row * 1024 + (H) * 64 + cc * 8, &QS[idx * 8]);      \
    }                                                                          \
    _Pragma("unroll") for (int r = 0; r < 2; r++) {                            \
      int idx = r * 512 + t;                                                   \
      int row = idx >> 3, pos = idx & 7;                                       \
      int cc = pos ^ (row & 7);                                                \
      async16(Kg + (size_t)row * 1024 + (H) * 64 + cc * 8, &KS[idx * 8]);      \
    }                                                                          \
  } while (0)

#define AW_COMPUTE(QS, KS, H) do {                                             \
    f32x4 sc[4][2];                                                            \
    _Pragma("unroll") for (int mt = 0; mt < 4; mt++)                           \
      _Pragma("unroll") for (int st2 = 0; st2 < 2; st2++)                      \
          sc[mt][st2] = (f32x4){0.f, 0.f, 0.f, 0.f};                           \
    _Pragma("unroll") for (int kh = 0; kh < 2; kh++) {                         \
      short8 af[4], bf[2];                                                     \
      _Pragma("unroll") for (int mt = 0; mt < 4; mt++) {                       \
        int m = wm * 64 + mt * 16 + li;                                        \
        int ch = (kh * 4 + quad) ^ (m & 7);                                    \
        af[mt] = *(const short8*)&QS[m * 64 + ch * 8];                         \
      }                                                                        \
      _Pragma("unroll") for (int st2 = 0; st2 < 2; st2++) {                    \
        int s = wn * 32 + st2 * 16 + li;                                       \
        int ch = (kh * 4 + quad) ^ (s & 7);                                    \
        bf[st2] = *(const short8*)&KS[s * 64 + ch * 8];                        \
      }                                                                        \
      _Pragma("unroll") for (int mt = 0; mt < 4; mt++)                         \
        _Pragma("unroll") for (int st2 = 0; st2 < 2; st2++)                    \
            sc[mt][st2] = __builtin_amdgcn_mfma_f32_16x16x32_bf16(             \
                af[mt], bf[st2], sc[mt][st2], 0, 0, 0);                        \
    }                                                                          \
    _Pragma("unroll") for (int mt = 0; mt < 4; mt++) {                         \
      f32x4 rd = *(const f32x4*)&rl[(H)][wm * 64 + mt * 16 + quad * 4];        \
      _Pragma("unroll") for (int st2 = 0; st2 < 2; st2++)                      \
        _Pragma("unroll") for (int rr = 0; rr < 4; rr++)                       \
            ws[mt][st2][rr] += __expf(sc[mt][st2][rr]) * rd[rr];               \
    }                                                                          \
  } while (0)

  // prologue: stage head 0 into buffer 0
  AW_STAGE(Qs0, Ks20, 0);

  for (int h = 0; h < 16; h += 2) {
    __syncthreads();                  // buf0 staged (vmcnt drained); buf1 reads done; rl visible
    if (h + 1 < 16) AW_STAGE(Qs1, Ks21, h + 1);
    AW_COMPUTE(Qs0, Ks20, h);
    __syncthreads();                  // buf1 staged; buf0 reads done
    if (h + 2 < 16) AW_STAGE(Qs0, Ks20, h + 2);
    AW_COMPUTE(Qs1, Ks21, h + 1);
  }
#undef AW_STAGE
#undef AW_COMPUTE

#pragma unroll
  for (int mt = 0; mt < 4; mt++)
#pragma unroll
    for (int st2 = 0; st2 < 2; st2++)
#pragma unroll
      for (int rr = 0; rr < 4; rr++) {
        int rg = l0 + wm * 64 + mt * 16 + quad * 4 + rr;
        int cg = s0 + wn * 32 + st2 * 16 + li;
        Wout[((size_t)n * 2048 + rg) * 2048 + cg] = ws[mt][st2][rr] * 0.0625f;
      }
}

// ---------------- launcher ----------------
extern "C" void kernel_launch(void* const* d_in, const int* in_sizes, int n_in,
                              void* d_out, int out_size, void* d_ws, size_t ws_size,
                              hipStream_t stream) {
  (void)in_sizes; (void)n_in; (void)out_size; (void)ws_size;
  const float* query = (const float*)d_in[0];
  const float* key_  = (const float*)d_in[1];
  const float* value = (const float*)d_in[2];
  const float* ipw   = (const float*)d_in[3];
  const float* ipb   = (const float*)d_in[4];
  const float* opw   = (const float*)d_in[5];
  const float* opb   = (const float*)d_in[6];
  float* out = (float*)d_out;
  char* ws = (char*)d_ws;
  const size_t MB = 1024 * 1024;

  // workspace map (104 MB): [0,48) Xq|Xk|Xv bf16 [n][seq][e]; [48,54) Wqkv bf16;
  // [54,56) Wout-proj bf16; [56,72) Q; [72,88) K; [88,104) V.
  // Aliases: Vt over Xk, CTX over Xq, Rden over Xv (all dead after QKV GEMM).
  short* Xq  = (short*)(ws + 0 * MB);
  short* Xk  = (short*)(ws + 16 * MB);
  short* Xv  = (short*)(ws + 32 * MB);
  short* Wb  = (short*)(ws + 48 * MB);
  short* Wob = (short*)(ws + 54 * MB);
  short* Qw  = (short*)(ws + 56 * MB);
  short* Kw  = (short*)(ws + 72 * MB);
  short* Vw  = (short*)(ws + 88 * MB);
  short* Vt  = Xk;
  short* Ctx = Xq;
  float* Rden = (float*)Xv;

  cvt_kernel<<<dim3(8192), dim3(256), 0, stream>>>(query, Xq, 1);
  cvt_kernel<<<dim3(8192), dim3(256), 0, stream>>>(key_,  Xk, 1);
  cvt_kernel<<<dim3(8192), dim3(256), 0, stream>>>(value, Xv, 1);
  cvt_kernel<<<dim3(3072), dim3(256), 0, stream>>>(ipw, Wb,  0);
  cvt_kernel<<<dim3(1024), dim3(256), 0, stream>>>(opw, Wob, 0);

  gemm_bt<false><<<dim3(8, 64, 3), dim3(256), 0, stream>>>(
      Xq, Wb, ipb, (void*)Qw, (long)8192 * 1024, (long)1024 * 1024, 1024,
      (long)8192 * 1024, 0.125f);

  vtrans<<<dim3(16, 32, 4), dim3(256), 0, stream>>>(Vw, Vt);

  attn_ctx<<<dim3(1024), dim3(512), 0, stream>>>(Qw, Kw, Vt, Ctx, Rden);
  attn_w<<<dim3(1024), dim3(512), 0, stream>>>(Qw, Kw, Rden, out + 8388608);

  gemm_bt<true><<<dim3(8, 64, 1), dim3(256), 0, stream>>>(
      Ctx, Wob, opb, (void*)out, 0, 0, 0, 0, 1.0f);
}

// Round 6
// 457.128 us; speedup vs baseline: 1.0306x; 1.0306x over previous
//
#include <hip/hip_runtime.h>

// L=2048, S=2048, N=4, E=1024, H=16, HD=64
using f32x4  = __attribute__((ext_vector_type(4))) float;
using short8 = __attribute__((ext_vector_type(8))) short;
using short4v = __attribute__((ext_vector_type(4))) short;

__device__ __forceinline__ short f2bf(float f) {
  unsigned u = __float_as_uint(f);
  u += 0x7fffu + ((u >> 16) & 1u);   // RNE
  return (short)(u >> 16);
}

// pack 2 f32 -> 2 bf16 (RNE) in one instruction; lo = a, hi = b
__device__ __forceinline__ unsigned cvt_pk_bf16(float a, float b) {
  unsigned r;
  asm("v_cvt_pk_bf16_f32 %0, %1, %2" : "=v"(r) : "v"(a), "v"(b));
  return r;
}

__device__ __forceinline__ void async16(const void* g, void* l) {
  __builtin_amdgcn_global_load_lds(
      (const __attribute__((address_space(1))) unsigned int*)g,
      (__attribute__((address_space(3))) unsigned int*)l, 16, 0, 0);
}

// ---------------- convert fp32 -> bf16 (optionally permute (L,N,E)->[n][l][e]) ----------------
__global__ void __launch_bounds__(256) cvt_kernel(const float* __restrict__ src,
                                                  short* __restrict__ dst,
                                                  int permute) {
  const int r = blockIdx.x;
  const int t = threadIdx.x;
  int srcRow = r;
  if (permute) { int n = r >> 11; int l = r & 2047; srcRow = l * 4 + n; }
  float4 v = *(const float4*)(src + (size_t)srcRow * 1024 + t * 4);
  short4v o;
  o.x = f2bf(v.x); o.y = f2bf(v.y); o.z = f2bf(v.z); o.w = f2bf(v.w);
  *(short4v*)(dst + (size_t)r * 1024 + t * 4) = o;
}

// ---------------- TN GEMM: C[M,1024] = A[M,1024] @ B[1024,1024]^T (+bias)(*scale) ----------------
template <bool F32OUT>
__global__ void __launch_bounds__(256) gemm_bt(const short* __restrict__ A0,
                                               const short* __restrict__ B0,
                                               const float* __restrict__ bias0,
                                               void* __restrict__ out0,
                                               long zA, long zB, long zBias, long zOut,
                                               float scale0) {
  __shared__ short As[128 * 32];
  __shared__ short Bs[128 * 32];
  const int bz = blockIdx.z;
  const short* A = A0 + (size_t)bz * zA;
  const short* B = B0 + (size_t)bz * zB;
  const float* bias = bias0 + (size_t)bz * zBias;
  const float scale = (bz == 0) ? scale0 : 1.0f;

  const int t = threadIdx.x;
  const int wave = t >> 6, lane = t & 63;
  const int quad = lane >> 4, li = lane & 15;
  const int wm = wave >> 1, wn = wave & 1;
  const int bm = blockIdx.y, bn = blockIdx.x;
  const short* Ablk = A + (size_t)bm * 128 * 1024;
  const short* Bblk = B + (size_t)bn * 128 * 1024;

  float bv[4];
#pragma unroll
  for (int nt = 0; nt < 4; nt++) bv[nt] = bias[bn * 128 + wn * 64 + nt * 16 + li];

  f32x4 acc[4][4];
#pragma unroll
  for (int mt = 0; mt < 4; mt++)
#pragma unroll
    for (int nt = 0; nt < 4; nt++) acc[mt][nt] = (f32x4){0.f, 0.f, 0.f, 0.f};

  for (int kk = 0; kk < 32; kk++) {
    const int k0 = kk * 32;
    __syncthreads();
#pragma unroll
    for (int r = 0; r < 2; r++) {
      int idx = r * 256 + t;
      int row = idx >> 2, pos = idx & 3;
      int c = pos ^ ((row >> 1) & 3);
      async16(Ablk + (size_t)row * 1024 + k0 + c * 8, &As[idx * 8]);
    }
#pragma unroll
    for (int r = 0; r < 2; r++) {
      int idx = r * 256 + t;
      int row = idx >> 2, pos = idx & 3;
      int c = pos ^ ((row >> 1) & 3);
      async16(Bblk + (size_t)row * 1024 + k0 + c * 8, &Bs[idx * 8]);
    }
    __syncthreads();

    short8 af[4], bf[4];
#pragma unroll
    for (int mt = 0; mt < 4; mt++) {
      int m = wm * 64 + mt * 16 + li;
      int pos = quad ^ ((m >> 1) & 3);
      af[mt] = *(const short8*)&As[m * 32 + pos * 8];
    }
#pragma unroll
    for (int nt = 0; nt < 4; nt++) {
      int nn = wn * 64 + nt * 16 + li;
      int pos = quad ^ ((nn >> 1) & 3);
      bf[nt] = *(const short8*)&Bs[nn * 32 + pos * 8];
    }
#pragma unroll
    for (int mt = 0; mt < 4; mt++)
#pragma unroll
      for (int nt = 0; nt < 4; nt++)
        acc[mt][nt] = __builtin_amdgcn_mfma_f32_16x16x32_bf16(af[mt], bf[nt], acc[mt][nt], 0, 0, 0);
  }

#pragma unroll
  for (int mt = 0; mt < 4; mt++)
#pragma unroll
    for (int nt = 0; nt < 4; nt++) {
      int cg = bn * 128 + wn * 64 + nt * 16 + li;
#pragma unroll
      for (int rr = 0; rr < 4; rr++) {
        int rg = bm * 128 + wm * 64 + mt * 16 + quad * 4 + rr;
        float v = (acc[mt][nt][rr] + bv[nt]) * scale;
        if (F32OUT)
          ((float*)out0)[(size_t)bz * zOut + (size_t)rg * 1024 + cg] = v;
        else
          ((short*)out0)[(size_t)bz * zOut + (size_t)rg * 1024 + cg] = f2bf(v);
      }
    }
}

// ---------------- V transpose: [n][s][e] -> [n][e][s] (bf16) ----------------
__global__ void __launch_bounds__(256) vtrans(const short* __restrict__ V,
                                              short* __restrict__ Vt) {
  __shared__ short tile[64][72];
  const int e0 = blockIdx.x * 64;
  const int s0 = blockIdx.y * 64;
  const int n = blockIdx.z;
  const int t = threadIdx.x;
#pragma unroll
  for (int r = 0; r < 2; r++) {
    int idx = r * 256 + t;
    int srow = idx >> 3, c = idx & 7;
    short8 v = *(const short8*)(V + (size_t)(n * 2048 + s0 + srow) * 1024 + e0 + c * 8);
    *(short8*)&tile[srow][c * 8] = v;
  }
  __syncthreads();
#pragma unroll
  for (int r = 0; r < 2; r++) {
    int idx = r * 256 + t;
    int erow = idx >> 3, c = idx & 7;
    short8 o;
#pragma unroll
    for (int j = 0; j < 8; j++) o[j] = tile[c * 8 + j][erow];
    *(short8*)(Vt + (size_t)(n * 1024 + e0 + erow) * 2048 + s0 + c * 8) = o;
  }
}

// ---------------- attn_ctx: head-parallel flash kernel ----------------
// grid 1024: bid -> h=bid&15, n=(bid>>4)&3, lc=bid>>6 (16 chunks of 128 rows).
// 8 waves x 16 q-rows. K/V 64x64 tiles staged in LDS (global_load_lds, XOR swizzle).
// Single-buffered (round-4 structure: 33.8 KB LDS -> 4 blocks/CU resident; the
// round-5 dbuf variant cost occupancy for no net gain -- kernel is VALU-bound).
// bf16 packing via v_cvt_pk_bf16_f32 (1 inst / 2 values) instead of 5-inst f2bf.
// Writes normalized Ctx (bf16, [l*4+n][e]) and Rden[n][h][l] = 1/denominator.
__global__ void __launch_bounds__(512, 4) attn_ctx(const short* __restrict__ Qws,
                                                   const short* __restrict__ Kws,
                                                   const short* __restrict__ Vtws,
                                                   short* __restrict__ Ctx,
                                                   float* __restrict__ Rden) {
  __shared__ short Ks[64 * 64];
  __shared__ short Vs[64 * 64];
  __shared__ short et[8][16][68];   // pad 68: quads land on distinct bank octets

  const int bid = blockIdx.x;
  const int h = bid & 15;
  const int n = (bid >> 4) & 3;
  const int lc = bid >> 6;
  const int t = threadIdx.x;
  const int wave = t >> 6, lane = t & 63;
  const int quad = lane >> 4, li = lane & 15;
  const int sw = li & 7;            // row&7 for fragment reads (row = x*16+li)
  const int l0 = lc * 128 + wave * 16;

  const size_t Kn = (size_t)n * 2048 * 1024;
  const size_t Vnb = ((size_t)n * 1024 + h * 64) * 2048;

  // persistent Q fragments (A-layout): rows l0+li, k = ks*32+quad*8
  short8 qf0 = *(const short8*)(Qws + Kn + (size_t)(l0 + li) * 1024 + h * 64 + quad * 8);
  short8 qf1 = *(const short8*)(Qws + Kn + (size_t)(l0 + li) * 1024 + h * 64 + 32 + quad * 8);

  // staging addresses: each wave stages 8 rows (1 KB) of K and of V per tile
  const int srow = lane >> 3;
  const int c = lane & 7;
  const int row8 = wave * 8 + srow;            // 0..63 tile row
  const int gch = c ^ (row8 & 7);              // XOR chunk swizzle
  const short* gK = Kws + Kn + (size_t)row8 * 1024 + h * 64 + gch * 8;
  const short* gV = Vtws + Vnb + (size_t)row8 * 2048 + gch * 8;
  short* lK = &Ks[0] + wave * 512 + lane * 8;
  short* lV = &Vs[0] + wave * 512 + lane * 8;

  f32x4 ctx[4];
  f32x4 den = (f32x4){0.f, 0.f, 0.f, 0.f};
#pragma unroll
  for (int nt = 0; nt < 4; nt++) ctx[nt] = (f32x4){0.f, 0.f, 0.f, 0.f};

  for (int it = 0; it < 32; it++) {
    __syncthreads();                  // prior tile reads done
    async16(gK, lK);
    async16(gV, lV);
    gK += 64 * 1024;                  // next 64 s-rows
    gV += 64;                         // next 64 s-cols
    __syncthreads();                  // staged data visible (vmcnt drained by barrier)

    // QK^T: sc[nts] over 64 s-cols
    f32x4 sc[4];
#pragma unroll
    for (int nts = 0; nts < 4; nts++) sc[nts] = (f32x4){0.f, 0.f, 0.f, 0.f};
#pragma unroll
    for (int nts = 0; nts < 4; nts++) {
      const int row = nts * 16 + li;
      short8 k0 = *(const short8*)&Ks[row * 64 + ((quad ^ sw) << 3)];
      short8 k1 = *(const short8*)&Ks[row * 64 + (((4 + quad) ^ sw) << 3)];
      sc[nts] = __builtin_amdgcn_mfma_f32_16x16x32_bf16(qf0, k0, sc[nts], 0, 0, 0);
      sc[nts] = __builtin_amdgcn_mfma_f32_16x16x32_bf16(qf1, k1, sc[nts], 0, 0, 0);
    }
    // exp, accumulate denom, write P^T tile (packed bf16 cvt) for A-operand re-layout
#pragma unroll
    for (int nts = 0; nts < 4; nts++) {
      float e0v = __expf(sc[nts][0]);
      float e1v = __expf(sc[nts][1]);
      float e2v = __expf(sc[nts][2]);
      float e3v = __expf(sc[nts][3]);
      den[0] += e0v; den[1] += e1v; den[2] += e2v; den[3] += e3v;
      unsigned p01 = cvt_pk_bf16(e0v, e1v);
      unsigned p23 = cvt_pk_bf16(e2v, e3v);
      et[wave][quad * 4 + 0][nts * 16 + li] = (short)p01;
      et[wave][quad * 4 + 1][nts * 16 + li] = (short)(p01 >> 16);
      et[wave][quad * 4 + 2][nts * 16 + li] = (short)p23;
      et[wave][quad * 4 + 3][nts * 16 + li] = (short)(p23 >> 16);
    }
    asm volatile("s_waitcnt lgkmcnt(0)" ::: "memory");
    short8 e0 = *(const short8*)&et[wave][li][quad * 8];
    short8 e1 = *(const short8*)&et[wave][li][32 + quad * 8];
#pragma unroll
    for (int nt = 0; nt < 4; nt++) {
      const int row = nt * 16 + li;
      short8 v0 = *(const short8*)&Vs[row * 64 + ((quad ^ sw) << 3)];
      short8 v1 = *(const short8*)&Vs[row * 64 + (((4 + quad) ^ sw) << 3)];
      ctx[nt] = __builtin_amdgcn_mfma_f32_16x16x32_bf16(e0, v0, ctx[nt], 0, 0, 0);
      ctx[nt] = __builtin_amdgcn_mfma_f32_16x16x32_bf16(e1, v1, ctx[nt], 0, 0, 0);
    }
  }

  // reduce denom over the 16 li lanes
#pragma unroll
  for (int off = 1; off < 16; off <<= 1)
#pragma unroll
    for (int rr = 0; rr < 4; rr++) den[rr] += __shfl_xor(den[rr], off);
  f32x4 rden;
#pragma unroll
  for (int rr = 0; rr < 4; rr++) rden[rr] = 1.0f / den[rr];

  if (li == 0) {
#pragma unroll
    for (int rr = 0; rr < 4; rr++)
      Rden[((size_t)n * 16 + h) * 2048 + l0 + quad * 4 + rr] = rden[rr];
  }

#pragma unroll
  for (int nt = 0; nt < 4; nt++) {
    unsigned p01 = cvt_pk_bf16(ctx[nt][0] * rden[0], ctx[nt][1] * rden[1]);
    unsigned p23 = cvt_pk_bf16(ctx[nt][2] * rden[2], ctx[nt][3] * rden[3]);
    const int col = h * 64 + nt * 16 + li;
    Ctx[((size_t)(l0 + quad * 4 + 0) * 4 + n) * 1024 + col] = (short)p01;
    Ctx[((size_t)(l0 + quad * 4 + 1) * 4 + n) * 1024 + col] = (short)(p01 >> 16);
    Ctx[((size_t)(l0 + quad * 4 + 2) * 4 + n) * 1024 + col] = (short)p23;
    Ctx[((size_t)(l0 + quad * 4 + 3) * 4 + n) * 1024 + col] = (short)(p23 >> 16);
  }
}

// ---------------- attn_w: weights output (LDS-tiled GEMM over heads) ----------------
// grid 1024: xcd = bid&7 -> n = xcd>>1; u = ((bid>>3)<<1)|(xcd&1) in [0,256):
// lt = u>>4, st = u&15  -> 128l x 128s output tile. 8 waves: wm = wave>>2 (2),
// wn = wave&3 (4); wave tile 64l x 32s. Per head: stage Q-slice + K-slice
// (16 KB each, global_load_lds + XOR chunk swizzle) into LDS, 16 MFMA/wave into
// fresh sc, fused exp*rden accumulate. Single-buffered (round-5 dbuf halved
// residency and regressed ~16 us).
__global__ void __launch_bounds__(512, 2) attn_w(const short* __restrict__ Qws,
                                                 const short* __restrict__ Kws,
                                                 const float* __restrict__ Rden,
                                                 float* __restrict__ Wout) {
  __shared__ short Qs[128 * 64];
  __shared__ short Ks2[128 * 64];
  __shared__ __align__(16) float rl[16][128];   // [h][l-idx] 1/denominator

  const int bid = blockIdx.x;
  const int xcd = bid & 7;
  const int n = xcd >> 1;
  const int u = ((bid >> 3) << 1) | (xcd & 1);   // 0..255
  const int lt = u >> 4;                          // 0..15
  const int st = u & 15;                          // 0..15
  const int l0 = lt * 128;
  const int s0 = st * 128;
  const int t = threadIdx.x;
  const int wave = t >> 6, lane = t & 63;
  const int quad = lane >> 4, li = lane & 15;
  const int wm = wave >> 2, wn = wave & 3;

  const size_t Kn = (size_t)n * 2048 * 1024;
  const short* Qg = Qws + Kn + (size_t)l0 * 1024;
  const short* Kg = Kws + Kn + (size_t)s0 * 1024;

  // stage rden: 16 heads x 128 l-rows (8 KB), 4 floats/thread
  {
    int idx = t * 4;
    int hh = idx >> 7, ll = idx & 127;
    *(float4*)&rl[hh][ll] =
        *(const float4*)(Rden + ((size_t)n * 16 + hh) * 2048 + l0 + ll);
  }

  f32x4 ws[4][2];
#pragma unroll
  for (int mt = 0; mt < 4; mt++)
#pragma unroll
    for (int st2 = 0; st2 < 2; st2++) ws[mt][st2] = (f32x4){0.f, 0.f, 0.f, 0.f};

  for (int h = 0; h < 16; h++) {
    __syncthreads();                  // prior head's LDS reads done (also covers rl stage)
#pragma unroll
    for (int r = 0; r < 2; r++) {
      int idx = r * 512 + t;
      int row = idx >> 3, pos = idx & 7;
      int c = pos ^ (row & 7);
      async16(Qg + (size_t)row * 1024 + h * 64 + c * 8, &Qs[idx * 8]);
    }
#pragma unroll
    for (int r = 0; r < 2; r++) {
      int idx = r * 512 + t;
      int row = idx >> 3, pos = idx & 7;
      int c = pos ^ (row & 7);
      async16(Kg + (size_t)row * 1024 + h * 64 + c * 8, &Ks2[idx * 8]);
    }
    __syncthreads();                  // staged data visible (vmcnt drained by barrier)

    f32x4 sc[4][2];
#pragma unroll
    for (int mt = 0; mt < 4; mt++)
#pragma unroll
      for (int st2 = 0; st2 < 2; st2++) sc[mt][st2] = (f32x4){0.f, 0.f, 0.f, 0.f};

#pragma unroll
    for (int kh = 0; kh < 2; kh++) {
      short8 af[4], bf[2];
#pragma unroll
      for (int mt = 0; mt < 4; mt++) {
        int m = wm * 64 + mt * 16 + li;
        int ch = (kh * 4 + quad) ^ (m & 7);
        af[mt] = *(const short8*)&Qs[m * 64 + ch * 8];
      }
#pragma unroll
      for (int st2 = 0; st2 < 2; st2++) {
        int s = wn * 32 + st2 * 16 + li;
        int ch = (kh * 4 + quad) ^ (s & 7);
        bf[st2] = *(const short8*)&Ks2[s * 64 + ch * 8];
      }
#pragma unroll
      for (int mt = 0; mt < 4; mt++)
#pragma unroll
        for (int st2 = 0; st2 < 2; st2++)
          sc[mt][st2] = __builtin_amdgcn_mfma_f32_16x16x32_bf16(af[mt], bf[st2],
                                                                sc[mt][st2], 0, 0, 0);
    }

#pragma unroll
    for (int mt = 0; mt < 4; mt++) {
      f32x4 rd = *(const f32x4*)&rl[h][wm * 64 + mt * 16 + quad * 4];
#pragma unroll
      for (int st2 = 0; st2 < 2; st2++)
#pragma unroll
        for (int rr = 0; rr < 4; rr++)
          ws[mt][st2][rr] += __expf(sc[mt][st2][rr]) * rd[rr];
    }
  }

#pragma unroll
  for (int mt = 0; mt < 4; mt++)
#pragma unroll
    for (int st2 = 0; st2 < 2; st2++)
#pragma unroll
      for (int rr = 0; rr < 4; rr++) {
        int rg = l0 + wm * 64 + mt * 16 + quad * 4 + rr;
        int cg = s0 + wn * 32 + st2 * 16 + li;
        Wout[((size_t)n * 2048 + rg) * 2048 + cg] = ws[mt][st2][rr] * 0.0625f;
      }
}

// ---------------- launcher ----------------
extern "C" void kernel_launch(void* const* d_in, const int* in_sizes, int n_in,
                              void* d_out, int out_size, void* d_ws, size_t ws_size,
                              hipStream_t stream) {
  (void)in_sizes; (void)n_in; (void)out_size; (void)ws_size;
  const float* query = (const float*)d_in[0];
  const float* key_  = (const float*)d_in[1];
  const float* value = (const float*)d_in[2];
  const float* ipw   = (const float*)d_in[3];
  const float* ipb   = (const float*)d_in[4];
  const float* opw   = (const float*)d_in[5];
  const float* opb   = (const float*)d_in[6];
  float* out = (float*)d_out;
  char* ws = (char*)d_ws;
  const size_t MB = 1024 * 1024;

  // workspace map (104 MB): [0,48) Xq|Xk|Xv bf16 [n][seq][e]; [48,54) Wqkv bf16;
  // [54,56) Wout-proj bf16; [56,72) Q; [72,88) K; [88,104) V.
  // Aliases: Vt over Xk, CTX over Xq, Rden over Xv (all dead after QKV GEMM).
  short* Xq  = (short*)(ws + 0 * MB);
  short* Xk  = (short*)(ws + 16 * MB);
  short* Xv  = (short*)(ws + 32 * MB);
  short* Wb  = (short*)(ws + 48 * MB);
  short* Wob = (short*)(ws + 54 * MB);
  short* Qw  = (short*)(ws + 56 * MB);
  short* Kw  = (short*)(ws + 72 * MB);
  short* Vw  = (short*)(ws + 88 * MB);
  short* Vt  = Xk;
  short* Ctx = Xq;
  float* Rden = (float*)Xv;

  cvt_kernel<<<dim3(8192), dim3(256), 0, stream>>>(query, Xq, 1);
  cvt_kernel<<<dim3(8192), dim3(256), 0, stream>>>(key_,  Xk, 1);
  cvt_kernel<<<dim3(8192), dim3(256), 0, stream>>>(value, Xv, 1);
  cvt_kernel<<<dim3(3072), dim3(256), 0, stream>>>(ipw, Wb,  0);
  cvt_kernel<<<dim3(1024), dim3(256), 0, stream>>>(opw, Wob, 0);

  gemm_bt<false><<<dim3(8, 64, 3), dim3(256), 0, stream>>>(
      Xq, Wb, ipb, (void*)Qw, (long)8192 * 1024, (long)1024 * 1024, 1024,
      (long)8192 * 1024, 0.125f);

  vtrans<<<dim3(16, 32, 4), dim3(256), 0, stream>>>(Vw, Vt);

  attn_ctx<<<dim3(1024), dim3(512), 0, stream>>>(Qw, Kw, Vt, Ctx, Rden);
  attn_w<<<dim3(1024), dim3(512), 0, stream>>>(Qw, Kw, Rden, out + 8388608);

  gemm_bt<true><<<dim3(8, 64, 1), dim3(256), 0, stream>>>(
      Ctx, Wob, opb, (void*)out, 0, 0, 0, 0, 1.0f);
}